// Round 6
// baseline (311.768 us; speedup 1.0000x reference)
//
#include <hip/hip_runtime.h>
#include <hip/hip_fp16.h>

#define OUT_DIM 128
#define N_FEAT 256
#define NPS 256              // nodes per super-bucket (A binning)
#define NS_MAX 400           // supers (391 actual)
#define CAP_S 4608           // payload slots per super (mean 4096 + 8 sigma)
#define EPT2 18              // CAP_S / SBLK2
#define SBLK1 256
#define EPT1 16
#define CHUNK1 (SBLK1 * EPT1)   // 4096
#define SBLK2 256               // == NPS
#define GBLK 256

typedef _Float16 f16;
typedef __attribute__((ext_vector_type(8))) _Float16 f16x8;
typedef __attribute__((ext_vector_type(4))) float f32x4;

// ---------- dense-X scatter: Xd[row][col] += val ----------
// CAS-based packed-fp16 add (no atomicAdd(__half2*) overload in ROCm 7.2).
// Duplicate (row,col) pairs (~50K expected) loop once more; semantics match
// segment_sum. DROPOUT=0 -> vals pass through unscaled.
__global__ __launch_bounds__(256) void scatter_x_kernel(
    const int* __restrict__ rows, const int* __restrict__ cols,
    const float* __restrict__ vals, int nnz, __half* __restrict__ Xd)
{
    int i = blockIdx.x * 256 + threadIdx.x;
    if (i >= nnz) return;
    int r = rows[i], c = cols[i];
    __half hv = __float2half(vals[i]);
    unsigned int* addr = (unsigned int*)(Xd + (size_t)r * N_FEAT + (c & ~1));
    bool hi = (c & 1) != 0;
    unsigned int old = *addr, assumed;
    do {
        assumed = old;
        __half2 h2 = *(__half2*)&assumed;
        if (hi) h2.y = __hadd(h2.y, hv);
        else    h2.x = __hadd(h2.x, hv);
        old = atomicCAS(addr, assumed, *(unsigned int*)&h2);
    } while (old != assumed);
}

// ---------- dense GEMM: XW = Xd(100K x 256) @ W(256 x 128), fp16 in/out ----------
// Block = 128 rows, 4 waves x 32 rows (2 row-tiles of 16). W^T staged in LDS
// (64 KB) swizzled (byte ^= (c&7)<<4) so B-frag ds_read_b128 avoids same-bank
// serialization. MFMA 16x16x32 f16; layouts (m89-verified family):
//   A: lane l -> row l&15, k = (l>>4)*8 + j (contiguous)
//   B: lane l -> col l&15, k = (l>>4)*8 + j
//   D: lane l -> col l&15, row = (l>>4)*4 + reg
__global__ __launch_bounds__(GBLK) void gemm_xw_kernel(
    const __half* __restrict__ Xd, const float* __restrict__ W,
    __half* __restrict__ XW, int n_nodes)
{
    __shared__ __align__(16) char sWT[N_FEAT * OUT_DIM * 2];   // 64 KB
    int tid = threadIdx.x;
    // stage W^T: element (c,k) at byte ((c*256+k)*2) ^ ((c&7)<<4)
    for (int t = tid; t < N_FEAT * OUT_DIM; t += GBLK) {
        int c = t & 127;            // W idx = k*128 + c = t  (coalesced reads)
        int k = t >> 7;
        int byte = ((c * N_FEAT + k) * 2) ^ ((c & 7) << 4);
        *(f16*)(sWT + byte) = (f16)W[t];
    }
    __syncthreads();

    int lane = tid & 63;
    int wv = tid >> 6;                       // 0..3
    int rbase = blockIdx.x * 128 + wv * 32;
    int lrow = lane & 15;
    int kb = lane >> 4;                      // 0..3
    f32x4 acc[2][8] = {};
    #pragma unroll
    for (int ks = 0; ks < 8; ++ks) {
        int k0 = ks * 32 + kb * 8;
        f16x8 a0 = {}, a1 = {};
        int r0 = rbase + lrow, r1 = rbase + 16 + lrow;
        if (r0 < n_nodes) a0 = *(const f16x8*)(Xd + (size_t)r0 * N_FEAT + k0);
        if (r1 < n_nodes) a1 = *(const f16x8*)(Xd + (size_t)r1 * N_FEAT + k0);
        #pragma unroll
        for (int nt = 0; nt < 8; ++nt) {
            int c = nt * 16 + lrow;
            int byte = ((c * N_FEAT + k0) * 2) ^ ((c & 7) << 4);
            f16x8 b = *(const f16x8*)(sWT + byte);
            acc[0][nt] = __builtin_amdgcn_mfma_f32_16x16x32_f16(a0, b, acc[0][nt], 0, 0, 0);
            acc[1][nt] = __builtin_amdgcn_mfma_f32_16x16x32_f16(a1, b, acc[1][nt], 0, 0, 0);
        }
    }
    #pragma unroll
    for (int rt = 0; rt < 2; ++rt) {
        #pragma unroll
        for (int nt = 0; nt < 8; ++nt) {
            #pragma unroll
            for (int i = 0; i < 4; ++i) {
                int r = rbase + rt * 16 + kb * 4 + i;
                int c = nt * 16 + lrow;
                if (r < n_nodes)
                    XW[(size_t)r * OUT_DIM + c] = __float2half(acc[rt][nt][i]);
            }
        }
    }
}

// ---------- pass 1 (A only): chunk-local counting sort + coalesced run write ----------
__global__ __launch_bounds__(SBLK1) void scatter1_kernel(
    const int* __restrict__ rows, const int* __restrict__ cols,
    const float* __restrict__ vals, int nnz,
    int* __restrict__ cur, int2* __restrict__ pay, int ns)
{
    __shared__ int2 s_stage[CHUNK1];            // 32 KB
    __shared__ unsigned short s_bin[CHUNK1];    // 8 KB
    __shared__ int s_hist[NS_MAX];
    __shared__ int s_excl[NS_MAX];
    __shared__ int s_gbase[NS_MAX];

    int tid = threadIdx.x;
    int start = (int)blockIdx.x * CHUNK1;
    int total = nnz - start; if (total > CHUNK1) total = CHUNK1;

    for (int i = tid; i < ns; i += SBLK1) s_hist[i] = 0;
    __syncthreads();

    int rr[EPT1]; int cc[EPT1]; float vv[EPT1];
    #pragma unroll
    for (int k = 0; k < EPT1; ++k) {
        int e = start + k * SBLK1 + tid;
        rr[k] = -1;
        if (e < nnz) {
            rr[k] = rows[e]; cc[k] = cols[e]; vv[k] = vals[e];
            atomicAdd(&s_hist[rr[k] >> 8], 1);
        }
    }
    __syncthreads();

    if (tid < 64) {
        int carry = 0;
        for (int seg = 0; seg < ns; seg += 64) {
            int idx = seg + tid;
            int x = (idx < ns) ? s_hist[idx] : 0;
            int incl = x;
            #pragma unroll
            for (int off = 1; off < 64; off <<= 1) {
                int y = __shfl_up(incl, off, 64);
                if (tid >= off) incl += y;
            }
            if (idx < ns) s_excl[idx] = carry + incl - x;
            carry += __shfl(incl, 63, 64);
        }
    }
    __syncthreads();

    for (int i = tid; i < ns; i += SBLK1) {
        int c = s_hist[i];
        s_gbase[i] = (c > 0) ? atomicAdd(&cur[i], c) : 0;
        s_hist[i] = 0;
    }
    __syncthreads();

    #pragma unroll
    for (int k = 0; k < EPT1; ++k) {
        if (rr[k] >= 0) {
            int b = rr[k] >> 8;
            int rl = rr[k] & 255;
            int pos = s_excl[b] + atomicAdd(&s_hist[b], 1);
            s_stage[pos] = make_int2((rl << 17) | cc[k], __float_as_int(vv[k]));
            s_bin[pos] = (unsigned short)b;
        }
    }
    __syncthreads();

    for (int i = tid; i < total; i += SBLK1) {
        int b = s_bin[i];
        int g = s_gbase[b] + (i - s_excl[b]);
        if (g < CAP_S)
            pay[(size_t)b * CAP_S + g] = s_stage[i];
    }
}

// ---------- pass 2 (A only): in-place node-sort of each super + node spans ----------
__global__ __launch_bounds__(SBLK2) void sort2_kernel(
    const int* __restrict__ cur, int2* __restrict__ pay,
    int2* __restrict__ row_span, int n_nodes)
{
    __shared__ int s_cnt[NPS];
    __shared__ int s_excl[NPS];
    int b = blockIdx.x;
    int tid = threadIdx.x;
    int count = cur[b]; if (count > CAP_S) count = CAP_S;
    int2* region = pay + (size_t)b * CAP_S;

    s_cnt[tid] = 0;
    __syncthreads();

    int2 er[EPT2];
    #pragma unroll
    for (int k = 0; k < EPT2; ++k) {
        int i = tid + k * SBLK2;
        er[k] = make_int2(-1, 0);
        if (i < count) {
            er[k] = region[i];
            atomicAdd(&s_cnt[((unsigned)er[k].x) >> 17], 1);
        }
    }
    __syncthreads();

    if (tid < 64) {
        int carry = 0;
        #pragma unroll
        for (int seg = 0; seg < NPS; seg += 64) {
            int x = s_cnt[seg + tid];
            int incl = x;
            #pragma unroll
            for (int off = 1; off < 64; off <<= 1) {
                int y = __shfl_up(incl, off, 64);
                if (tid >= off) incl += y;
            }
            s_excl[seg + tid] = carry + incl - x;
            carry += __shfl(incl, 63, 64);
        }
    }
    __syncthreads();

    int g = b * NPS + tid;
    if (g < n_nodes)
        row_span[g] = make_int2(b * CAP_S + s_excl[tid], s_cnt[tid]);
    __syncthreads();

    #pragma unroll
    for (int k = 0; k < EPT2; ++k) {
        if (er[k].x >= 0) {
            int rl = ((unsigned)er[k].x) >> 17;
            int pos = atomicAdd(&s_excl[rl], 1);
            region[pos] = make_int2(er[k].x & 0x1FFFF, er[k].y);
        }
    }
}

// ---------- stage 2: out[node,:] = relu( sum val * XW[col,:] ) ----------
// FROZEN (round-2 form, best measured 60.0 us): do not touch.
__global__ __launch_bounds__(GBLK, 4) void gather_agg_kernel(
    const int2* __restrict__ row_span, const int2* __restrict__ pay,
    const __half* __restrict__ XW, float* __restrict__ out, int n_nodes)
{
    int tid = threadIdx.x;
    int lane = tid & 15;
    int node = blockIdx.x * 16 + (tid >> 4);
    if (node >= n_nodes) return;
    int2 span = row_span[node];                     // A spans
    int s = span.x, cnt = span.y;
    const int4* Xv = (const int4*)XW;
    float a0=0,a1=0,a2=0,a3=0,a4=0,a5=0,a6=0,a7=0;
    int2 pl = make_int2(0, 0);
    if (lane < cnt) pl = pay[s + lane];
    for (int base = 0; base < cnt; base += 16) {
        int4 w[16];
        #pragma unroll
        for (int j = 0; j < 16; ++j) {
            int c = __shfl(pl.x, j, 16);            // pad lanes: c=0 (L1-hot row)
            w[j] = Xv[(size_t)((c << 4) | lane)];
        }
        int2 pln = make_int2(0, 0);
        if (base + 16 + lane < cnt) pln = pay[s + base + 16 + lane];
        #pragma unroll
        for (int j = 0; j < 16; ++j) {
            float v = __int_as_float(__shfl(pl.y, j, 16));  // pad lanes: v=0
            union { int4 i4; __half2 h[4]; } u;
            u.i4 = w[j];
            float2 f0 = __half22float2(u.h[0]);
            float2 f1 = __half22float2(u.h[1]);
            float2 f2 = __half22float2(u.h[2]);
            float2 f3 = __half22float2(u.h[3]);
            a0 += v * f0.x; a1 += v * f0.y; a2 += v * f1.x; a3 += v * f1.y;
            a4 += v * f2.x; a5 += v * f2.y; a6 += v * f3.x; a7 += v * f3.y;
        }
        pl = pln;
    }
    float4 lo, hi;
    lo.x = fmaxf(a0, 0.f); lo.y = fmaxf(a1, 0.f);
    lo.z = fmaxf(a2, 0.f); lo.w = fmaxf(a3, 0.f);
    hi.x = fmaxf(a4, 0.f); hi.y = fmaxf(a5, 0.f);
    hi.z = fmaxf(a6, 0.f); hi.w = fmaxf(a7, 0.f);
    float4* orow = (float4*)(out + (size_t)node * OUT_DIM);
    orow[2 * lane]     = lo;
    orow[2 * lane + 1] = hi;
}

extern "C" void kernel_launch(void* const* d_in, const int* in_sizes, int n_in,
                              void* d_out, int out_size, void* d_ws, size_t ws_size,
                              hipStream_t stream) {
    const int*   feat_rows = (const int*)d_in[0];
    const int*   feat_cols = (const int*)d_in[1];
    const float* feat_vals = (const float*)d_in[2];
    const int*   adj_rows  = (const int*)d_in[3];
    const int*   adj_cols  = (const int*)d_in[4];
    const float* adj_vals  = (const float*)d_in[5];
    const float* W         = (const float*)d_in[6];
    float*       out       = (float*)d_out;

    const int nnz_x   = in_sizes[0];
    const int nnz_a   = in_sizes[3];
    const int n_nodes = out_size / OUT_DIM;
    const int ns      = (n_nodes + NPS - 1) / NPS;   // 391

    // ---- workspace layout (~92 MB) ----
    char* p = (char*)d_ws;
    __half* XW   = (__half*)p;  p += (size_t)n_nodes * OUT_DIM * sizeof(__half); // 25.6 MB
    __half* Xd   = (__half*)p;  p += (size_t)n_nodes * N_FEAT * sizeof(__half);  // 51.2 MB
    p = (char*)(((uintptr_t)p + 15) & ~(uintptr_t)15);
    int2* pay    = (int2*)p;    p += (size_t)ns * CAP_S * sizeof(int2);          // 14.4 MB
    int2* row_span = (int2*)p;  p += (size_t)n_nodes * sizeof(int2);             // 0.8 MB
    int* cur     = (int*)p;     p += (size_t)ns * sizeof(int);

    (void)hipMemsetAsync(Xd, 0, (size_t)n_nodes * N_FEAT * sizeof(__half), stream);
    (void)hipMemsetAsync(cur, 0, (size_t)ns * sizeof(int), stream);

    // X side: dense scatter + MFMA GEMM (replaces X-sort + gather_xw)
    scatter_x_kernel<<<(nnz_x + 255) / 256, 256, 0, stream>>>(
        feat_rows, feat_cols, feat_vals, nnz_x, Xd);

    // A side: proven sort pipeline (A only)
    const int nCkA = (nnz_a + CHUNK1 - 1) / CHUNK1;
    scatter1_kernel<<<nCkA, SBLK1, 0, stream>>>(
        adj_rows, adj_cols, adj_vals, nnz_a, cur, pay, ns);
    sort2_kernel<<<ns, SBLK2, 0, stream>>>(cur, pay, row_span, n_nodes);

    gemm_xw_kernel<<<(n_nodes + 127) / 128, GBLK, 0, stream>>>(Xd, W, XW, n_nodes);

    const int gnb = (n_nodes + 15) / 16;
    gather_agg_kernel<<<gnb, GBLK, 0, stream>>>(row_span, pay, XW, out, n_nodes);
}

// Round 7
// 274.808 us; speedup vs baseline: 1.1345x; 1.1345x over previous
//
#include <hip/hip_runtime.h>
#include <hip/hip_fp16.h>

#define OUT_DIM 128
#define N_FEAT 256
#define NPS 256              // nodes per super-bucket
#define NS_MAX 400           // supers per matrix (391 actual)
#define CAP_S 4608           // payload slots per super (mean 4096 + 8 sigma)
#define EPT2 18              // CAP_S / SBLK2
#define SBLK1 256
#define EPT1 16
#define CHUNK1 (SBLK1 * EPT1)   // 4096
#define SBLK2 256               // == NPS
#define GBLK 256
#define DBLK 256

typedef _Float16 f16;
typedef __attribute__((ext_vector_type(8))) _Float16 f16x8;
typedef __attribute__((ext_vector_type(4))) float f32x4;

// ---------- pass 1: chunk-local counting sort (A and X), coalesced run write ----------
__global__ __launch_bounds__(SBLK1) void scatter1_kernel(
    const int* __restrict__ adj_rows, const int* __restrict__ adj_cols,
    const float* __restrict__ adj_vals, int nnz_a, int nCkA,
    const int* __restrict__ feat_rows, const int* __restrict__ feat_cols,
    const float* __restrict__ feat_vals, int nnz_x,
    int* __restrict__ cur, int2* __restrict__ pay, int ns)
{
    __shared__ int2 s_stage[CHUNK1];            // 32 KB
    __shared__ unsigned short s_bin[CHUNK1];    // 8 KB
    __shared__ int s_hist[NS_MAX];
    __shared__ int s_excl[NS_MAX];
    __shared__ int s_gbase[NS_MAX];

    int tid = threadIdx.x;
    bool isA = ((int)blockIdx.x < nCkA);
    const int* rows; const int* cols; const float* vals;
    int nnz, start, matbase;
    if (isA) {
        rows = adj_rows; cols = adj_cols; vals = adj_vals; nnz = nnz_a;
        start = (int)blockIdx.x * CHUNK1; matbase = 0;
    } else {
        rows = feat_rows; cols = feat_cols; vals = feat_vals; nnz = nnz_x;
        start = ((int)blockIdx.x - nCkA) * CHUNK1; matbase = ns;
    }
    int total = nnz - start; if (total > CHUNK1) total = CHUNK1;

    for (int i = tid; i < ns; i += SBLK1) s_hist[i] = 0;
    __syncthreads();

    int rr[EPT1]; int cc[EPT1]; float vv[EPT1];
    #pragma unroll
    for (int k = 0; k < EPT1; ++k) {
        int e = start + k * SBLK1 + tid;
        rr[k] = -1;
        if (e < nnz) {
            rr[k] = rows[e]; cc[k] = cols[e]; vv[k] = vals[e];
            atomicAdd(&s_hist[rr[k] >> 8], 1);
        }
    }
    __syncthreads();

    // wave 0: exclusive scan of s_hist[0..ns) -> s_excl
    if (tid < 64) {
        int carry = 0;
        for (int seg = 0; seg < ns; seg += 64) {
            int idx = seg + tid;
            int x = (idx < ns) ? s_hist[idx] : 0;
            int incl = x;
            #pragma unroll
            for (int off = 1; off < 64; off <<= 1) {
                int y = __shfl_up(incl, off, 64);
                if (tid >= off) incl += y;
            }
            if (idx < ns) s_excl[idx] = carry + incl - x;
            carry += __shfl(incl, 63, 64);
        }
    }
    __syncthreads();

    for (int i = tid; i < ns; i += SBLK1) {
        int c = s_hist[i];
        s_gbase[i] = (c > 0) ? atomicAdd(&cur[matbase + i], c) : 0;
        s_hist[i] = 0;   // reuse as rank cursor
    }
    __syncthreads();

    #pragma unroll
    for (int k = 0; k < EPT1; ++k) {
        if (rr[k] >= 0) {
            int b = rr[k] >> 8;
            int rl = rr[k] & 255;
            int pos = s_excl[b] + atomicAdd(&s_hist[b], 1);
            s_stage[pos] = make_int2((rl << 17) | cc[k], __float_as_int(vv[k]));
            s_bin[pos] = (unsigned short)b;
        }
    }
    __syncthreads();

    for (int i = tid; i < total; i += SBLK1) {
        int b = s_bin[i];
        int g = s_gbase[b] + (i - s_excl[b]);
        if (g < CAP_S)
            pay[(size_t)(matbase + b) * CAP_S + g] = s_stage[i];
    }
}

// ---------- pass 2 (A only): in-place node-sort of each super + node spans ----------
__global__ __launch_bounds__(SBLK2) void sort2_kernel(
    const int* __restrict__ cur, int2* __restrict__ pay,
    int2* __restrict__ row_span, int n_nodes)
{
    __shared__ int s_cnt[NPS];
    __shared__ int s_excl[NPS];
    int b = blockIdx.x;
    int tid = threadIdx.x;
    int count = cur[b]; if (count > CAP_S) count = CAP_S;
    int2* region = pay + (size_t)b * CAP_S;

    s_cnt[tid] = 0;
    __syncthreads();

    int2 er[EPT2];
    #pragma unroll
    for (int k = 0; k < EPT2; ++k) {
        int i = tid + k * SBLK2;
        er[k] = make_int2(-1, 0);
        if (i < count) {
            er[k] = region[i];
            atomicAdd(&s_cnt[((unsigned)er[k].x) >> 17], 1);
        }
    }
    __syncthreads();

    if (tid < 64) {
        int carry = 0;
        #pragma unroll
        for (int seg = 0; seg < NPS; seg += 64) {
            int x = s_cnt[seg + tid];
            int incl = x;
            #pragma unroll
            for (int off = 1; off < 64; off <<= 1) {
                int y = __shfl_up(incl, off, 64);
                if (tid >= off) incl += y;
            }
            s_excl[seg + tid] = carry + incl - x;
            carry += __shfl(incl, 63, 64);
        }
    }
    __syncthreads();

    int g = b * NPS + tid;
    if (g < n_nodes)
        row_span[g] = make_int2(b * CAP_S + s_excl[tid], s_cnt[tid]);
    __syncthreads();

    #pragma unroll
    for (int k = 0; k < EPT2; ++k) {
        if (er[k].x >= 0) {
            int rl = ((unsigned)er[k].x) >> 17;
            int pos = atomicAdd(&s_excl[rl], 1);
            region[pos] = make_int2(er[k].x & 0x1FFFF, er[k].y);
        }
    }
}

// ---------- densify X: quarter-super LDS tile, no global atomics, no memset ----------
// Block = 64 nodes. Zero fp32 tile -> stream super bucket -> LDS atomicAdd
// (duplicates summed like segment_sum) -> coalesced fp16 row write-out.
__global__ __launch_bounds__(DBLK) void densify_x_kernel(
    const int* __restrict__ cur, const int2* __restrict__ pay,
    __half* __restrict__ Xd, int ns, int n_nodes)
{
    __shared__ float tile[64][N_FEAT];          // 64 KB -> 2 blocks/CU
    int tid = threadIdx.x;
    int sb = blockIdx.x >> 2;                   // super
    int q  = blockIdx.x & 3;                    // quarter (rl bits 7:6)
    int count = cur[ns + sb]; if (count > CAP_S) count = CAP_S;
    const int2* region = pay + (size_t)(ns + sb) * CAP_S;

    float4* tf = (float4*)&tile[0][0];
    #pragma unroll
    for (int i = tid; i < 64 * N_FEAT / 4; i += DBLK)
        tf[i] = make_float4(0.f, 0.f, 0.f, 0.f);
    __syncthreads();

    for (int i = tid; i < count; i += DBLK) {
        int2 e = region[i];
        int rl = ((unsigned)e.x) >> 17;
        if ((rl >> 6) == q)
            atomicAdd(&tile[rl & 63][e.x & 0x1FFFF], __int_as_float(e.y));
    }
    __syncthreads();

    int nodebase = sb * NPS + q * 64;
    for (int i = tid; i < 64 * 128; i += DBLK) {
        int r = i >> 7, cp = i & 127;           // row, half2-column
        int node = nodebase + r;
        if (node < n_nodes) {
            __half2 hv = __floats2half2_rn(tile[r][2 * cp], tile[r][2 * cp + 1]);
            *(__half2*)(Xd + (size_t)node * N_FEAT + 2 * cp) = hv;
        }
    }
}

// ---------- dense GEMM: XW = Xd(100K x 256) @ W(256 x 128) ----------
// PROVEN CORRECT in round 6 (passed refcheck) — unchanged.
__global__ __launch_bounds__(GBLK) void gemm_xw_kernel(
    const __half* __restrict__ Xd, const float* __restrict__ W,
    __half* __restrict__ XW, int n_nodes)
{
    __shared__ __align__(16) char sWT[N_FEAT * OUT_DIM * 2];   // 64 KB
    int tid = threadIdx.x;
    for (int t = tid; t < N_FEAT * OUT_DIM; t += GBLK) {
        int c = t & 127;            // W idx = k*128 + c = t  (coalesced reads)
        int k = t >> 7;
        int byte = ((c * N_FEAT + k) * 2) ^ ((c & 7) << 4);
        *(f16*)(sWT + byte) = (f16)W[t];
    }
    __syncthreads();

    int lane = tid & 63;
    int wv = tid >> 6;                       // 0..3
    int rbase = blockIdx.x * 128 + wv * 32;
    int lrow = lane & 15;
    int kb = lane >> 4;                      // 0..3
    f32x4 acc[2][8] = {};
    #pragma unroll
    for (int ks = 0; ks < 8; ++ks) {
        int k0 = ks * 32 + kb * 8;
        f16x8 a0 = {}, a1 = {};
        int r0 = rbase + lrow, r1 = rbase + 16 + lrow;
        if (r0 < n_nodes) a0 = *(const f16x8*)(Xd + (size_t)r0 * N_FEAT + k0);
        if (r1 < n_nodes) a1 = *(const f16x8*)(Xd + (size_t)r1 * N_FEAT + k0);
        #pragma unroll
        for (int nt = 0; nt < 8; ++nt) {
            int c = nt * 16 + lrow;
            int byte = ((c * N_FEAT + k0) * 2) ^ ((c & 7) << 4);
            f16x8 b = *(const f16x8*)(sWT + byte);
            acc[0][nt] = __builtin_amdgcn_mfma_f32_16x16x32_f16(a0, b, acc[0][nt], 0, 0, 0);
            acc[1][nt] = __builtin_amdgcn_mfma_f32_16x16x32_f16(a1, b, acc[1][nt], 0, 0, 0);
        }
    }
    #pragma unroll
    for (int rt = 0; rt < 2; ++rt) {
        #pragma unroll
        for (int nt = 0; nt < 8; ++nt) {
            #pragma unroll
            for (int i = 0; i < 4; ++i) {
                int r = rbase + rt * 16 + kb * 4 + i;
                int c = nt * 16 + lrow;
                if (r < n_nodes)
                    XW[(size_t)r * OUT_DIM + c] = __float2half(acc[rt][nt][i]);
            }
        }
    }
}

// ---------- stage 2: out[node,:] = relu( sum val * XW[col,:] ) ----------
// FROZEN (round-2 form, best measured 60.0 us): do not touch.
__global__ __launch_bounds__(GBLK, 4) void gather_agg_kernel(
    const int2* __restrict__ row_span, const int2* __restrict__ pay,
    const __half* __restrict__ XW, float* __restrict__ out, int n_nodes)
{
    int tid = threadIdx.x;
    int lane = tid & 15;
    int node = blockIdx.x * 16 + (tid >> 4);
    if (node >= n_nodes) return;
    int2 span = row_span[node];                     // A spans
    int s = span.x, cnt = span.y;
    const int4* Xv = (const int4*)XW;
    float a0=0,a1=0,a2=0,a3=0,a4=0,a5=0,a6=0,a7=0;
    int2 pl = make_int2(0, 0);
    if (lane < cnt) pl = pay[s + lane];
    for (int base = 0; base < cnt; base += 16) {
        int4 w[16];
        #pragma unroll
        for (int j = 0; j < 16; ++j) {
            int c = __shfl(pl.x, j, 16);            // pad lanes: c=0 (L1-hot row)
            w[j] = Xv[(size_t)((c << 4) | lane)];
        }
        int2 pln = make_int2(0, 0);
        if (base + 16 + lane < cnt) pln = pay[s + base + 16 + lane];
        #pragma unroll
        for (int j = 0; j < 16; ++j) {
            float v = __int_as_float(__shfl(pl.y, j, 16));  // pad lanes: v=0
            union { int4 i4; __half2 h[4]; } u;
            u.i4 = w[j];
            float2 f0 = __half22float2(u.h[0]);
            float2 f1 = __half22float2(u.h[1]);
            float2 f2 = __half22float2(u.h[2]);
            float2 f3 = __half22float2(u.h[3]);
            a0 += v * f0.x; a1 += v * f0.y; a2 += v * f1.x; a3 += v * f1.y;
            a4 += v * f2.x; a5 += v * f2.y; a6 += v * f3.x; a7 += v * f3.y;
        }
        pl = pln;
    }
    float4 lo, hi;
    lo.x = fmaxf(a0, 0.f); lo.y = fmaxf(a1, 0.f);
    lo.z = fmaxf(a2, 0.f); lo.w = fmaxf(a3, 0.f);
    hi.x = fmaxf(a4, 0.f); hi.y = fmaxf(a5, 0.f);
    hi.z = fmaxf(a6, 0.f); hi.w = fmaxf(a7, 0.f);
    float4* orow = (float4*)(out + (size_t)node * OUT_DIM);
    orow[2 * lane]     = lo;
    orow[2 * lane + 1] = hi;
}

extern "C" void kernel_launch(void* const* d_in, const int* in_sizes, int n_in,
                              void* d_out, int out_size, void* d_ws, size_t ws_size,
                              hipStream_t stream) {
    const int*   feat_rows = (const int*)d_in[0];
    const int*   feat_cols = (const int*)d_in[1];
    const float* feat_vals = (const float*)d_in[2];
    const int*   adj_rows  = (const int*)d_in[3];
    const int*   adj_cols  = (const int*)d_in[4];
    const float* adj_vals  = (const float*)d_in[5];
    const float* W         = (const float*)d_in[6];
    float*       out       = (float*)d_out;

    const int nnz_x   = in_sizes[0];
    const int nnz_a   = in_sizes[3];
    const int n_nodes = out_size / OUT_DIM;
    const int ns      = (n_nodes + NPS - 1) / NPS;   // 391

    // ---- workspace layout (~107 MB) ----
    char* p = (char*)d_ws;
    __half* XW   = (__half*)p;  p += (size_t)n_nodes * OUT_DIM * sizeof(__half); // 25.6 MB
    __half* Xd   = (__half*)p;  p += (size_t)n_nodes * N_FEAT * sizeof(__half);  // 51.2 MB
    p = (char*)(((uintptr_t)p + 15) & ~(uintptr_t)15);
    int2* pay    = (int2*)p;    p += (size_t)2 * ns * CAP_S * sizeof(int2);      // 28.8 MB
    int2* row_span = (int2*)p;  p += (size_t)n_nodes * sizeof(int2);             // 0.8 MB
    int* cur     = (int*)p;     p += (size_t)2 * ns * sizeof(int);

    (void)hipMemsetAsync(cur, 0, (size_t)2 * ns * sizeof(int), stream);

    const int nCkA = (nnz_a + CHUNK1 - 1) / CHUNK1;
    const int nCkX = (nnz_x + CHUNK1 - 1) / CHUNK1;
    scatter1_kernel<<<nCkA + nCkX, SBLK1, 0, stream>>>(
        adj_rows, adj_cols, adj_vals, nnz_a, nCkA,
        feat_rows, feat_cols, feat_vals, nnz_x,
        cur, pay, ns);

    sort2_kernel<<<ns, SBLK2, 0, stream>>>(cur, pay, row_span, n_nodes);

    densify_x_kernel<<<4 * ns, DBLK, 0, stream>>>(cur, pay, Xd, ns, n_nodes);

    gemm_xw_kernel<<<(n_nodes + 127) / 128, GBLK, 0, stream>>>(Xd, W, XW, n_nodes);

    const int gnb = (n_nodes + 15) / 16;
    gather_agg_kernel<<<gnb, GBLK, 0, stream>>>(row_span, pay, XW, out, n_nodes);
}